// Round 18
// baseline (85.728 us; speedup 1.0000x reference)
//
#include <hip/hip_runtime.h>
#include <hip/hip_bf16.h>
#include <cstdint>

typedef __attribute__((ext_vector_type(8))) __bf16 bf16x8;
typedef __attribute__((ext_vector_type(4))) float f32x4;
typedef __attribute__((ext_vector_type(8))) unsigned short u16x8;
typedef __attribute__((ext_vector_type(4))) unsigned short u16x4;
typedef __attribute__((ext_vector_type(4))) unsigned int u32x4;

#define NEG_INF (-__builtin_inff())

__device__ __forceinline__ unsigned short f2bf(float f) {
    unsigned int u = __builtin_bit_cast(unsigned int, f);
    u += 0x7FFFu + ((u >> 16) & 1u);
    return (unsigned short)(u >> 16);
}
__device__ __forceinline__ float bf2f(unsigned short u) {
    return __builtin_bit_cast(float, (unsigned int)u << 16);
}

__device__ __forceinline__ void gload16(const void* g, void* l) {
    __builtin_amdgcn_global_load_lds(
        (__attribute__((address_space(1))) void*)(uintptr_t)g,
        (__attribute__((address_space(3))) void*)(uint32_t)(uintptr_t)l, 16, 0, 0);
}

// ------- merged prep (vectorized): z<4 = transpose+cast weights (64x64 tiles); z==4 = cast x -------
__global__ void prep_kernel(const float* __restrict__ x, const float* __restrict__ W0,
                            const float* __restrict__ W1, const float* __restrict__ W2,
                            const float* __restrict__ W3, unsigned short* __restrict__ xb,
                            unsigned short* __restrict__ Wcat, unsigned short* __restrict__ Wot) {
    __shared__ float t[64][68];
    const int tid = threadIdx.x;
    const int z = blockIdx.z;
    if (z == 4) {
        const int base = (blockIdx.y * 16 + blockIdx.x) * 256 + tid;
        #pragma unroll
        for (int v = 0; v < 8; ++v) {
            size_t u = (size_t)v * 65536 + base;
            const float4* p = (const float4*)x + u * 2;
            float4 a = p[0], c = p[1];
            u16x8 o;
            o[0] = f2bf(a.x); o[1] = f2bf(a.y); o[2] = f2bf(a.z); o[3] = f2bf(a.w);
            o[4] = f2bf(c.x); o[5] = f2bf(c.y); o[6] = f2bf(c.z); o[7] = f2bf(c.w);
            ((u16x8*)xb)[u] = o;
        }
        return;
    }
    const float* src = (z == 0) ? W0 : (z == 1) ? W1 : (z == 2) ? W2 : W3;
    unsigned short* dst = (z < 3) ? (Wcat + (size_t)z * 1024 * 1024) : Wot;
    const int n0 = blockIdx.x * 64, k0 = blockIdx.y * 64;
    #pragma unroll
    for (int i = 0; i < 4; ++i) {
        int idx = i * 256 + tid;
        int kr = idx >> 4, c4 = idx & 15;
        *(float4*)&t[kr][c4 * 4] = *(const float4*)&src[(size_t)(k0 + kr) * 1024 + n0 + c4 * 4];
    }
    __syncthreads();
    #pragma unroll
    for (int i = 0; i < 2; ++i) {
        int idx = i * 256 + tid;
        int nr = idx >> 3, c8 = idx & 7;
        u16x8 o;
        #pragma unroll
        for (int j = 0; j < 8; ++j) o[j] = f2bf(t[c8 * 8 + j][nr]);
        *(u16x8*)&dst[(size_t)(n0 + nr) * 1024 + k0 + c8 * 8] = o;
    }
}

// ---------------- fused QKV GEMM (128x128, 3 blocks/CU): A * Wcat^T -> Q,K row-major; V transposed ----------------
__global__ __launch_bounds__(256, 2)
void gemm_qkv_kernel(const unsigned short* __restrict__ A, const unsigned short* __restrict__ Bt,
                     unsigned short* __restrict__ Qb, unsigned short* __restrict__ Kb,
                     unsigned short* __restrict__ Vtb) {
    __shared__ unsigned short As[128 * 64];
    __shared__ unsigned short Bs[128 * 64];
    const int tid = threadIdx.x;
    const int w = tid >> 6, l = tid & 63;
    const int lr = l & 15, lg = l >> 4;
    const int wr = w >> 1, wc = w & 1;
    const int id = blockIdx.y * 24 + blockIdx.x;
    const int swz = (id & 7) * 96 + (id >> 3);
    const int m0 = (swz / 24) * 128;
    const int n0 = (swz % 24) * 128;
    const int K = 1024;

    f32x4 acc[4][4] = {};

    for (int k0 = 0; k0 < 1024; k0 += 64) {
        #pragma unroll
        for (int p = 0; p < 4; ++p) {
            int seg = p * 4 + w;
            int row = seg * 8 + (l >> 3);
            int c16 = (l & 7) ^ (row & 7);
            gload16(A  + (size_t)(m0 + row) * K + k0 + c16 * 8, &As[seg * 512]);
            gload16(Bt + (size_t)(n0 + row) * K + k0 + c16 * 8, &Bs[seg * 512]);
        }
        __syncthreads();
        #pragma unroll
        for (int ks = 0; ks < 2; ++ks) {
            bf16x8 af[4], bfr[4];
            #pragma unroll
            for (int i = 0; i < 4; ++i) {
                int ra = wr * 64 + i * 16 + lr;
                af[i] = *(const bf16x8*)&As[ra * 64 + (((ks << 2) | lg) ^ (ra & 7)) * 8];
                int rb = wc * 64 + i * 16 + lr;
                bfr[i] = *(const bf16x8*)&Bs[rb * 64 + (((ks << 2) | lg) ^ (rb & 7)) * 8];
            }
            #pragma unroll
            for (int i = 0; i < 4; ++i)
                #pragma unroll
                for (int j = 0; j < 4; ++j)
                    acc[i][j] = __builtin_amdgcn_mfma_f32_16x16x32_bf16(af[i], bfr[j], acc[i][j], 0, 0, 0);
        }
        __syncthreads();
    }

    const int seg = n0 >> 10;        // 0=Q, 1=K, 2=V
    const int n0l = n0 & 1023;
    if (seg < 2) {
        unsigned short* C = (seg == 0) ? Qb : Kb;
        const float sc = (seg == 0) ? 0.125f * 1.44269504f : 1.0f;
        #pragma unroll
        for (int i = 0; i < 4; ++i)
            #pragma unroll
            for (int j = 0; j < 4; ++j) {
                int n = n0l + wc * 64 + j * 16 + lr;
                #pragma unroll
                for (int r = 0; r < 4; ++r) {
                    int m = m0 + wr * 64 + i * 16 + lg * 4 + r;
                    C[(size_t)m * 1024 + n] = f2bf(acc[i][j][r] * sc);
                }
            }
    } else {
        #pragma unroll
        for (int i = 0; i < 4; ++i)
            #pragma unroll
            for (int j = 0; j < 4; ++j) {
                int n = n0l + wc * 64 + j * 16 + lr;
                int mb = m0 + wr * 64 + i * 16 + lg * 4;
                int bb = mb >> 11, s = mb & 2047;
                int s6 = s & 63;
                int kp = (((s6 >> 4) & 1) << 5) | (((s6 >> 2) & 3) << 3) | (((s6 >> 5) & 1) << 2);
                int sp = (s & ~63) | kp;
                u16x4 o;
                #pragma unroll
                for (int r = 0; r < 4; ++r) o[r] = f2bf(acc[i][j][r]);
                *(u16x4*)&Vtb[((size_t)(bb * 1024 + n)) * 2048 + sp] = o;
            }
    }
}

// ---------------- flash attention (causal) v14: 3-deep LDS ring, 1 barrier + 1 vmcnt per tile ----------------
// 2-tile prefetch covers HBM latency. Per tile u: vmcnt(4) [own u-loads landed;
// u+1 in flight] -> s_barrier [all waves' u-data visible + buf free] ->
// issue u+2 -> compute (no further waits). m=0 softmax, zero-shuffle P.
static __device__ const unsigned char QS_TAB[24] = {
    7,15,14,14,13,6,12,5,
    15,13,12,10,11,10,11,9,
    0,1,2,3,8,8,9,4};
static __device__ const unsigned char TY_TAB[24] = {   // 0=single, 1=half0, 2=half1
    0,2,1,2,2,0,2,0,
    1,1,1,1,1,2,2,2,
    0,0,0,0,1,2,1,0};

__global__ __launch_bounds__(256, 3)
void flash_attn_kernel(const unsigned short* __restrict__ Q, const unsigned short* __restrict__ Kg,
                       const unsigned short* __restrict__ Vt, unsigned short* __restrict__ ctx,
                       unsigned short* __restrict__ P_O, float* __restrict__ P_l) {
    __shared__ unsigned short Ks[3][4096];
    __shared__ unsigned short Vs[3][4096];
    const int tid = threadIdx.x, w = tid >> 6, l = tid & 63;
    const int lr = l & 15, lg = l >> 4;

    const int level = blockIdx.x >> 5;
    const int bh = blockIdx.x & 31;
    const int qs = QS_TAB[level], ty = TY_TAB[level];
    const int Tf = 2 * qs + 2, mid = qs + 1;
    const int t0 = (ty == 2) ? mid : 0;
    const int t1 = (ty == 1) ? mid : Tf;
    const int T = t1 - t0;
    const int b = bh >> 4, h = bh & 15;
    const int qw = qs * 128 + w * 32;

    const int srow8 = w * 8 + (l >> 3);
    const int scol  = (l & 7) ^ (srow8 & 7);
    const unsigned short* Kbase = Kg + (size_t)(b * 2048) * 1024 + h * 64;
    const unsigned short* Vbase = Vt + (size_t)(b * 1024 + h * 64) * 2048;

    const __bf16 one = (__bf16)1.0f;
    const bf16x8 ones = {one, one, one, one, one, one, one, one};

    bf16x8 qf[2][2];
    #pragma unroll
    for (int mi = 0; mi < 2; ++mi)
        #pragma unroll
        for (int ks = 0; ks < 2; ++ks)
            qf[mi][ks] = *(const bf16x8*)&Q[(size_t)(b * 2048 + qw + mi * 16 + lr) * 1024 + h * 64 + ks * 32 + lg * 8];

    f32x4 lacc[2] = {};
    f32x4 oacc[2][4] = {};

    // prologue: stage u=0 and u=1 (clamped) into ring slots 0,1
    #pragma unroll
    for (int u = 0; u < 2; ++u) {
        int ts = (u < T) ? t0 + u : t0;
        #pragma unroll
        for (int p = 0; p < 2; ++p) {
            gload16(Kbase + (size_t)(ts * 64 + p * 32 + srow8) * 1024 + scol * 8, &Ks[u][(p * 32 + w * 8) * 64]);
            gload16(Vbase + (size_t)(p * 32 + srow8) * 2048 + ts * 64 + scol * 8, &Vs[u][(p * 32 + w * 8) * 64]);
        }
    }

    for (int u = 0; u < T; ++u) {
        const int t = t0 + u;
        const int cur = u % 3;
        const int k0 = t * 64;

        asm volatile("s_waitcnt vmcnt(4)" ::: "memory");   // own u-loads landed; u+1 in flight
        __builtin_amdgcn_s_barrier();                      // all waves: u-data visible, slot (u+2)%3 free

        // issue u+2 into ring slot (u+2)%3 (clamped dummy keeps vmcnt pattern)
        {
            const int nxt = (u + 2) % 3;
            const int ts = (u + 2 < T) ? t + 2 : t0;
            #pragma unroll
            for (int p = 0; p < 2; ++p) {
                gload16(Kbase + (size_t)(ts * 64 + p * 32 + srow8) * 1024 + scol * 8, &Ks[nxt][(p * 32 + w * 8) * 64]);
                gload16(Vbase + (size_t)(p * 32 + srow8) * 2048 + ts * 64 + scol * 8, &Vs[nxt][(p * 32 + w * 8) * 64]);
            }
        }

        // ---- S^T via mfma(K, Q) ----
        f32x4 sf[2][4] = {};
        __builtin_amdgcn_s_setprio(1);
        #pragma unroll
        for (int ks = 0; ks < 2; ++ks) {
            bf16x8 kf[4];
            #pragma unroll
            for (int ni = 0; ni < 4; ++ni) {
                int rk = ni * 16 + lr;
                kf[ni] = *(const bf16x8*)&Ks[cur][rk * 64 + (((ks << 2) | lg) ^ (rk & 7)) * 8];
            }
            #pragma unroll
            for (int ni = 0; ni < 4; ++ni)
                #pragma unroll
                for (int mi = 0; mi < 2; ++mi)
                    sf[mi][ni] = __builtin_amdgcn_mfma_f32_16x16x32_bf16(kf[ni], qf[mi][ks], sf[mi][ni], 0, 0, 0);
        }
        __builtin_amdgcn_s_setprio(0);

        u32x4 pa0u[2], pa1u[2];
        #pragma unroll
        for (int mi = 0; mi < 2; ++mi) {
            if (t >= Tf - 2) {
                #pragma unroll
                for (int ni = 0; ni < 4; ++ni)
                    #pragma unroll
                    for (int r = 0; r < 4; ++r)
                        if (k0 + ni * 16 + lg * 4 + r > qw + mi * 16 + lr) sf[mi][ni][r] = NEG_INF;
            }
            #pragma unroll
            for (int ni = 0; ni < 4; ++ni)
                #pragma unroll
                for (int r = 0; r < 4; ++r)
                    sf[mi][ni][r] = __builtin_amdgcn_exp2f(sf[mi][ni][r]);

            asm("v_cvt_pk_bf16_f32 %0, %1, %2" : "=v"(pa0u[mi][0]) : "v"(sf[mi][0][0]), "v"(sf[mi][0][1]));
            asm("v_cvt_pk_bf16_f32 %0, %1, %2" : "=v"(pa0u[mi][1]) : "v"(sf[mi][0][2]), "v"(sf[mi][0][3]));
            asm("v_cvt_pk_bf16_f32 %0, %1, %2" : "=v"(pa0u[mi][2]) : "v"(sf[mi][2][0]), "v"(sf[mi][2][1]));
            asm("v_cvt_pk_bf16_f32 %0, %1, %2" : "=v"(pa0u[mi][3]) : "v"(sf[mi][2][2]), "v"(sf[mi][2][3]));
            asm("v_cvt_pk_bf16_f32 %0, %1, %2" : "=v"(pa1u[mi][0]) : "v"(sf[mi][1][0]), "v"(sf[mi][1][1]));
            asm("v_cvt_pk_bf16_f32 %0, %1, %2" : "=v"(pa1u[mi][1]) : "v"(sf[mi][1][2]), "v"(sf[mi][1][3]));
            asm("v_cvt_pk_bf16_f32 %0, %1, %2" : "=v"(pa1u[mi][2]) : "v"(sf[mi][3][0]), "v"(sf[mi][3][1]));
            asm("v_cvt_pk_bf16_f32 %0, %1, %2" : "=v"(pa1u[mi][3]) : "v"(sf[mi][3][2]), "v"(sf[mi][3][3]));

            lacc[mi] = __builtin_amdgcn_mfma_f32_16x16x32_bf16(
                __builtin_bit_cast(bf16x8, pa0u[mi]), ones, lacc[mi], 0, 0, 0);
            lacc[mi] = __builtin_amdgcn_mfma_f32_16x16x32_bf16(
                __builtin_bit_cast(bf16x8, pa1u[mi]), ones, lacc[mi], 0, 0, 0);
        }

        // ---- O += P V (V(u) landed with K(u); no extra wait) ----
        __builtin_amdgcn_s_setprio(1);
        #pragma unroll
        for (int ks = 0; ks < 2; ++ks) {
            bf16x8 vb[4];
            #pragma unroll
            for (int ni = 0; ni < 4; ++ni) {
                int rv = ni * 16 + lr;
                vb[ni] = *(const bf16x8*)&Vs[cur][rv * 64 + (((ks << 2) | lg) ^ (rv & 7)) * 8];
            }
            #pragma unroll
            for (int mi = 0; mi < 2; ++mi) {
                bf16x8 pa = __builtin_bit_cast(bf16x8, ks ? pa1u[mi] : pa0u[mi]);
                #pragma unroll
                for (int ni = 0; ni < 4; ++ni)
                    oacc[mi][ni] = __builtin_amdgcn_mfma_f32_16x16x32_bf16(pa, vb[ni], oacc[mi][ni], 0, 0, 0);
            }
        }
        __builtin_amdgcn_s_setprio(0);
    }

    if (ty == 0) {
        #pragma unroll
        for (int mi = 0; mi < 2; ++mi)
            #pragma unroll
            for (int r = 0; r < 4; ++r) {
                float inv = 1.0f / lacc[mi][r];
                int q = qw + mi * 16 + lg * 4 + r;
                size_t base = (size_t)(b * 2048 + q) * 1024 + h * 64 + lr;
                #pragma unroll
                for (int ni = 0; ni < 4; ++ni)
                    ctx[base + ni * 16] = f2bf(oacc[mi][ni][r] * inv);
            }
    } else {
        const int pidx = ((qs - 8) * 32 + bh) * 2 + (ty - 1);
        unsigned short* po = P_O + (size_t)pidx * 8192;
        #pragma unroll
        for (int mi = 0; mi < 2; ++mi)
            #pragma unroll
            for (int r = 0; r < 4; ++r) {
                int rowl = w * 32 + mi * 16 + lg * 4 + r;
                #pragma unroll
                for (int ni = 0; ni < 4; ++ni)
                    po[rowl * 64 + ni * 16 + lr] = f2bf(oacc[mi][ni][r]);
            }
        if (lr == 0) {
            #pragma unroll
            for (int mi = 0; mi < 2; ++mi)
                #pragma unroll
                for (int r = 0; r < 4; ++r)
                    P_l[pidx * 128 + w * 32 + mi * 16 + lg * 4 + r] = lacc[mi][r];
        }
    }
}

// ---------------- combine split-KV partials (shared m=0): ctx = (O0+O1)/(l0+l1) ----------------
__global__ __launch_bounds__(256)
void combine_kernel(const unsigned short* __restrict__ P_O, const float* __restrict__ P_l,
                    unsigned short* __restrict__ ctx) {
    const int qs = 8 + (blockIdx.x >> 5);
    const int bh = blockIdx.x & 31;
    const int b = bh >> 4, h = bh & 15;
    const int p0 = ((qs - 8) * 32 + bh) * 2, p1 = p0 + 1;
    const int t = threadIdx.x;
    const int row = t >> 1, half = t & 1;
    const float inv = 1.0f / (P_l[p0 * 128 + row] + P_l[p1 * 128 + row]);
    const u16x8* o0 = (const u16x8*)&P_O[(size_t)p0 * 8192 + row * 64 + half * 32];
    const u16x8* o1 = (const u16x8*)&P_O[(size_t)p1 * 8192 + row * 64 + half * 32];
    unsigned short* dst = ctx + (size_t)(b * 2048 + qs * 128 + row) * 1024 + h * 64 + half * 32;
    #pragma unroll
    for (int v = 0; v < 4; ++v) {
        u16x8 a = o0[v], c = o1[v], o;
        #pragma unroll
        for (int j = 0; j < 8; ++j)
            o[j] = f2bf((bf2f(a[j]) + bf2f(c[j])) * inv);
        ((u16x8*)dst)[v] = o;
    }
}

// ---------------- output GEMM: ctx(4096x1024) @ Wo + bo -> f32 ----------------
__global__ __launch_bounds__(256, 4)
void gemm_out_kernel(const unsigned short* __restrict__ A, const unsigned short* __restrict__ Bt,
                     float* __restrict__ C, const float* __restrict__ bias) {
    __shared__ unsigned short As[128 * 64];
    __shared__ unsigned short Bs[64 * 64];
    const int tid = threadIdx.x;
    const int w = tid >> 6, l = tid & 63;
    const int lr = l & 15, lg = l >> 4;
    const int wr = w >> 1, wc = w & 1;
    const int id = blockIdx.y * 16 + blockIdx.x;
    const int swz = (id & 7) * 64 + (id >> 3);
    const int m0 = (swz >> 4) * 128;
    const int n0 = (swz & 15) * 64;
    const int K = 1024;

    f32x4 acc[4][2] = {};

    for (int k0 = 0; k0 < 1024; k0 += 64) {
        #pragma unroll
        for (int p = 0; p < 4; ++p) {
            int seg = p * 4 + w;
            int row = seg * 8 + (l >> 3);
            int c16 = (l & 7) ^ (row & 7);
            gload16(A + (size_t)(m0 + row) * K + k0 + c16 * 8, &As[seg * 512]);
        }
        #pragma unroll
        for (int p = 0; p < 2; ++p) {
            int seg = p * 4 + w;
            int row = seg * 8 + (l >> 3);
            int c16 = (l & 7) ^ (row & 7);
            gload16(Bt + (size_t)(n0 + row) * K + k0 + c16 * 8, &Bs[seg * 512]);
        }
        __syncthreads();
        #pragma unroll
        for (int ks = 0; ks < 2; ++ks) {
            bf16x8 af[4], bfr[2];
            #pragma unroll
            for (int i = 0; i < 4; ++i) {
                int ra = wr * 64 + i * 16 + lr;
                af[i] = *(const bf16x8*)&As[ra * 64 + (((ks << 2) | lg) ^ (ra & 7)) * 8];
            }
            #pragma unroll
            for (int j = 0; j < 2; ++j) {
                int rb = wc * 32 + j * 16 + lr;
                bfr[j] = *(const bf16x8*)&Bs[rb * 64 + (((ks << 2) | lg) ^ (rb & 7)) * 8];
            }
            #pragma unroll
            for (int i = 0; i < 4; ++i)
                #pragma unroll
                for (int j = 0; j < 2; ++j)
                    acc[i][j] = __builtin_amdgcn_mfma_f32_16x16x32_bf16(af[i], bfr[j], acc[i][j], 0, 0, 0);
        }
        __syncthreads();
    }

    #pragma unroll
    for (int i = 0; i < 4; ++i)
        #pragma unroll
        for (int j = 0; j < 2; ++j) {
            int n = n0 + wc * 32 + j * 16 + lr;
            float bv = bias[n];
            #pragma unroll
            for (int r = 0; r < 4; ++r) {
                int m = m0 + wr * 64 + i * 16 + lg * 4 + r;
                C[(size_t)m * 1024 + n] = acc[i][j][r] + bv;
            }
        }
}

extern "C" void kernel_launch(void* const* d_in, const int* in_sizes, int n_in,
                              void* d_out, int out_size, void* d_ws, size_t ws_size,
                              hipStream_t stream) {
    (void)in_sizes; (void)n_in; (void)out_size; (void)ws_size;
    const float* x  = (const float*)d_in[0];
    const float* Wq = (const float*)d_in[1];
    const float* Wk = (const float*)d_in[2];
    const float* Wv = (const float*)d_in[3];
    const float* Wo = (const float*)d_in[4];
    const float* bo = (const float*)d_in[5];
    float* out = (float*)d_out;

    char* ws = (char*)d_ws;
    const size_t MB = 1024 * 1024;
    unsigned short* xb   = (unsigned short*)(ws);            // 8 MB: x bf16 (dead after qkv -> P_O)
    unsigned short* Wcat = (unsigned short*)(ws + 8  * MB);  // 6 MB (dead after qkv -> P_l)
    unsigned short* Wot  = (unsigned short*)(ws + 14 * MB);  // 2 MB: Wo^T
    unsigned short* Qb   = (unsigned short*)(ws + 16 * MB);  // 8 MB (pre-scaled by 0.125*log2e)
    unsigned short* Kb   = (unsigned short*)(ws + 24 * MB);  // 8 MB
    unsigned short* Vtb  = (unsigned short*)(ws + 32 * MB);  // 8 MB: V^T sigma-permuted
    unsigned short* Cxb  = (unsigned short*)(ws + 40 * MB);  // 8 MB: ctx bf16

    unsigned short* P_O  = (unsigned short*)(ws);            // 8 MB: 512 x 128x64 bf16 partials
    float*          P_l  = (float*)(ws + 8 * MB);            // 256 KB: 512 x 128 l values

    prep_kernel<<<dim3(16, 16, 5), 256, 0, stream>>>(x, Wq, Wk, Wv, Wo, xb, Wcat, Wot);
    gemm_qkv_kernel<<<dim3(24, 32), 256, 0, stream>>>(xb, Wcat, Qb, Kb, Vtb);
    flash_attn_kernel<<<768, 256, 0, stream>>>(Qb, Kb, Vtb, Cxb, P_O, P_l);
    combine_kernel<<<256, 256, 0, stream>>>(P_O, P_l, Cxb);
    gemm_out_kernel<<<dim3(16, 32), 256, 0, stream>>>(Cxb, Wot, out, bo);
}

// Round 19
// 84.561 us; speedup vs baseline: 1.0138x; 1.0138x over previous
//
#include <hip/hip_runtime.h>
#include <hip/hip_bf16.h>
#include <cstdint>

typedef __attribute__((ext_vector_type(8))) __bf16 bf16x8;
typedef __attribute__((ext_vector_type(4))) float f32x4;
typedef __attribute__((ext_vector_type(8))) unsigned short u16x8;
typedef __attribute__((ext_vector_type(4))) unsigned short u16x4;
typedef __attribute__((ext_vector_type(4))) unsigned int u32x4;

#define NEG_INF (-__builtin_inff())

__device__ __forceinline__ unsigned short f2bf(float f) {
    unsigned int u = __builtin_bit_cast(unsigned int, f);
    u += 0x7FFFu + ((u >> 16) & 1u);
    return (unsigned short)(u >> 16);
}
__device__ __forceinline__ float bf2f(unsigned short u) {
    return __builtin_bit_cast(float, (unsigned int)u << 16);
}

__device__ __forceinline__ void gload16(const void* g, void* l) {
    __builtin_amdgcn_global_load_lds(
        (__attribute__((address_space(1))) void*)(uintptr_t)g,
        (__attribute__((address_space(3))) void*)(uint32_t)(uintptr_t)l, 16, 0, 0);
}

// ------- merged prep (vectorized): z<4 = transpose+cast weights (64x64 tiles); z==4 = cast x -------
__global__ void prep_kernel(const float* __restrict__ x, const float* __restrict__ W0,
                            const float* __restrict__ W1, const float* __restrict__ W2,
                            const float* __restrict__ W3, unsigned short* __restrict__ xb,
                            unsigned short* __restrict__ Wcat, unsigned short* __restrict__ Wot) {
    __shared__ float t[64][68];
    const int tid = threadIdx.x;
    const int z = blockIdx.z;
    if (z == 4) {
        const int base = (blockIdx.y * 16 + blockIdx.x) * 256 + tid;
        #pragma unroll
        for (int v = 0; v < 8; ++v) {
            size_t u = (size_t)v * 65536 + base;
            const float4* p = (const float4*)x + u * 2;
            float4 a = p[0], c = p[1];
            u16x8 o;
            o[0] = f2bf(a.x); o[1] = f2bf(a.y); o[2] = f2bf(a.z); o[3] = f2bf(a.w);
            o[4] = f2bf(c.x); o[5] = f2bf(c.y); o[6] = f2bf(c.z); o[7] = f2bf(c.w);
            ((u16x8*)xb)[u] = o;
        }
        return;
    }
    const float* src = (z == 0) ? W0 : (z == 1) ? W1 : (z == 2) ? W2 : W3;
    unsigned short* dst = (z < 3) ? (Wcat + (size_t)z * 1024 * 1024) : Wot;
    const int n0 = blockIdx.x * 64, k0 = blockIdx.y * 64;
    #pragma unroll
    for (int i = 0; i < 4; ++i) {
        int idx = i * 256 + tid;
        int kr = idx >> 4, c4 = idx & 15;
        *(float4*)&t[kr][c4 * 4] = *(const float4*)&src[(size_t)(k0 + kr) * 1024 + n0 + c4 * 4];
    }
    __syncthreads();
    #pragma unroll
    for (int i = 0; i < 2; ++i) {
        int idx = i * 256 + tid;
        int nr = idx >> 3, c8 = idx & 7;
        u16x8 o;
        #pragma unroll
        for (int j = 0; j < 8; ++j) o[j] = f2bf(t[c8 * 8 + j][nr]);
        *(u16x8*)&dst[(size_t)(n0 + nr) * 1024 + k0 + c8 * 8] = o;
    }
}

// ---------------- fused QKV GEMM (128x128): A * Wcat^T -> Q,K row-major; V transposed ----------------
// launch_bounds(256,4): cap VGPR at 128 so all 768 blocks (3/CU) are co-resident in one round.
__global__ __launch_bounds__(256, 4)
void gemm_qkv_kernel(const unsigned short* __restrict__ A, const unsigned short* __restrict__ Bt,
                     unsigned short* __restrict__ Qb, unsigned short* __restrict__ Kb,
                     unsigned short* __restrict__ Vtb) {
    __shared__ unsigned short As[128 * 64];
    __shared__ unsigned short Bs[128 * 64];
    const int tid = threadIdx.x;
    const int w = tid >> 6, l = tid & 63;
    const int lr = l & 15, lg = l >> 4;
    const int wr = w >> 1, wc = w & 1;
    const int id = blockIdx.y * 24 + blockIdx.x;
    const int swz = (id & 7) * 96 + (id >> 3);
    const int m0 = (swz / 24) * 128;
    const int n0 = (swz % 24) * 128;
    const int K = 1024;

    f32x4 acc[4][4] = {};

    for (int k0 = 0; k0 < 1024; k0 += 64) {
        #pragma unroll
        for (int p = 0; p < 4; ++p) {
            int seg = p * 4 + w;
            int row = seg * 8 + (l >> 3);
            int c16 = (l & 7) ^ (row & 7);
            gload16(A  + (size_t)(m0 + row) * K + k0 + c16 * 8, &As[seg * 512]);
            gload16(Bt + (size_t)(n0 + row) * K + k0 + c16 * 8, &Bs[seg * 512]);
        }
        __syncthreads();
        #pragma unroll
        for (int ks = 0; ks < 2; ++ks) {
            bf16x8 af[4], bfr[4];
            #pragma unroll
            for (int i = 0; i < 4; ++i) {
                int ra = wr * 64 + i * 16 + lr;
                af[i] = *(const bf16x8*)&As[ra * 64 + (((ks << 2) | lg) ^ (ra & 7)) * 8];
                int rb = wc * 64 + i * 16 + lr;
                bfr[i] = *(const bf16x8*)&Bs[rb * 64 + (((ks << 2) | lg) ^ (rb & 7)) * 8];
            }
            #pragma unroll
            for (int i = 0; i < 4; ++i)
                #pragma unroll
                for (int j = 0; j < 4; ++j)
                    acc[i][j] = __builtin_amdgcn_mfma_f32_16x16x32_bf16(af[i], bfr[j], acc[i][j], 0, 0, 0);
        }
        __syncthreads();
    }

    const int seg = n0 >> 10;        // 0=Q, 1=K, 2=V
    const int n0l = n0 & 1023;
    if (seg < 2) {
        unsigned short* C = (seg == 0) ? Qb : Kb;
        const float sc = (seg == 0) ? 0.125f * 1.44269504f : 1.0f;
        #pragma unroll
        for (int i = 0; i < 4; ++i)
            #pragma unroll
            for (int j = 0; j < 4; ++j) {
                int n = n0l + wc * 64 + j * 16 + lr;
                #pragma unroll
                for (int r = 0; r < 4; ++r) {
                    int m = m0 + wr * 64 + i * 16 + lg * 4 + r;
                    C[(size_t)m * 1024 + n] = f2bf(acc[i][j][r] * sc);
                }
            }
    } else {
        #pragma unroll
        for (int i = 0; i < 4; ++i)
            #pragma unroll
            for (int j = 0; j < 4; ++j) {
                int n = n0l + wc * 64 + j * 16 + lr;
                int mb = m0 + wr * 64 + i * 16 + lg * 4;
                int bb = mb >> 11, s = mb & 2047;
                int s6 = s & 63;
                int kp = (((s6 >> 4) & 1) << 5) | (((s6 >> 2) & 3) << 3) | (((s6 >> 5) & 1) << 2);
                int sp = (s & ~63) | kp;
                u16x4 o;
                #pragma unroll
                for (int r = 0; r < 4; ++r) o[r] = f2bf(acc[i][j][r]);
                *(u16x4*)&Vtb[((size_t)(bb * 1024 + n)) * 2048 + sp] = o;
            }
    }
}

// ---------------- flash attention (causal) v12: NO max tracking (fixed m=0) ----------------
static __device__ const unsigned char QS_TAB[24] = {
    7,15,14,14,13,6,12,5,
    15,13,12,10,11,10,11,9,
    0,1,2,3,8,8,9,4};
static __device__ const unsigned char TY_TAB[24] = {   // 0=single, 1=half0, 2=half1
    0,2,1,2,2,0,2,0,
    1,1,1,1,1,2,2,2,
    0,0,0,0,1,2,1,0};

__global__ __launch_bounds__(256, 4)
void flash_attn_kernel(const unsigned short* __restrict__ Q, const unsigned short* __restrict__ Kg,
                       const unsigned short* __restrict__ Vt, unsigned short* __restrict__ ctx,
                       unsigned short* __restrict__ P_O, float* __restrict__ P_l) {
    __shared__ unsigned short Ks[2][4096];
    __shared__ unsigned short Vs[2][4096];
    const int tid = threadIdx.x, w = tid >> 6, l = tid & 63;
    const int lr = l & 15, lg = l >> 4;

    const int level = blockIdx.x >> 5;
    const int bh = blockIdx.x & 31;
    const int qs = QS_TAB[level], ty = TY_TAB[level];
    const int Tf = 2 * qs + 2, mid = qs + 1;
    const int t0 = (ty == 2) ? mid : 0;
    const int t1 = (ty == 1) ? mid : Tf;
    const int b = bh >> 4, h = bh & 15;
    const int qw = qs * 128 + w * 32;

    const int srow8 = w * 8 + (l >> 3);
    const int scol  = (l & 7) ^ (srow8 & 7);
    const unsigned short* Kbase = Kg + (size_t)(b * 2048) * 1024 + h * 64;
    const unsigned short* Vbase = Vt + (size_t)(b * 1024 + h * 64) * 2048;

    const __bf16 one = (__bf16)1.0f;
    const bf16x8 ones = {one, one, one, one, one, one, one, one};

    bf16x8 qf[2][2];
    #pragma unroll
    for (int mi = 0; mi < 2; ++mi)
        #pragma unroll
        for (int ks = 0; ks < 2; ++ks)
            qf[mi][ks] = *(const bf16x8*)&Q[(size_t)(b * 2048 + qw + mi * 16 + lr) * 1024 + h * 64 + ks * 32 + lg * 8];

    f32x4 lacc[2] = {};
    f32x4 oacc[2][4] = {};

    #pragma unroll
    for (int p = 0; p < 2; ++p)
        gload16(Kbase + (size_t)(t0 * 64 + p * 32 + srow8) * 1024 + scol * 8, &Ks[0][(p * 32 + w * 8) * 64]);

    for (int t = t0; t < t1; ++t) {
        const int cur = (t - t0) & 1;
        const int k0 = t * 64;
        #pragma unroll
        for (int p = 0; p < 2; ++p)
            gload16(Vbase + (size_t)(p * 32 + srow8) * 2048 + k0 + scol * 8, &Vs[cur][(p * 32 + w * 8) * 64]);
        const int ktn = (t + 1 < t1) ? t + 1 : t0;
        #pragma unroll
        for (int p = 0; p < 2; ++p)
            gload16(Kbase + (size_t)(ktn * 64 + p * 32 + srow8) * 1024 + scol * 8, &Ks[cur ^ 1][(p * 32 + w * 8) * 64]);

        asm volatile("s_waitcnt vmcnt(4)" ::: "memory");
        __builtin_amdgcn_s_barrier();

        f32x4 sf[2][4] = {};
        __builtin_amdgcn_s_setprio(1);
        #pragma unroll
        for (int ks = 0; ks < 2; ++ks) {
            bf16x8 kf[4];
            #pragma unroll
            for (int ni = 0; ni < 4; ++ni) {
                int rk = ni * 16 + lr;
                kf[ni] = *(const bf16x8*)&Ks[cur][rk * 64 + (((ks << 2) | lg) ^ (rk & 7)) * 8];
            }
            #pragma unroll
            for (int ni = 0; ni < 4; ++ni)
                #pragma unroll
                for (int mi = 0; mi < 2; ++mi)
                    sf[mi][ni] = __builtin_amdgcn_mfma_f32_16x16x32_bf16(kf[ni], qf[mi][ks], sf[mi][ni], 0, 0, 0);
        }
        __builtin_amdgcn_s_setprio(0);

        u32x4 pa0u[2], pa1u[2];
        #pragma unroll
        for (int mi = 0; mi < 2; ++mi) {
            if (t >= Tf - 2) {
                #pragma unroll
                for (int ni = 0; ni < 4; ++ni)
                    #pragma unroll
                    for (int r = 0; r < 4; ++r)
                        if (k0 + ni * 16 + lg * 4 + r > qw + mi * 16 + lr) sf[mi][ni][r] = NEG_INF;
            }
            #pragma unroll
            for (int ni = 0; ni < 4; ++ni)
                #pragma unroll
                for (int r = 0; r < 4; ++r)
                    sf[mi][ni][r] = __builtin_amdgcn_exp2f(sf[mi][ni][r]);

            asm("v_cvt_pk_bf16_f32 %0, %1, %2" : "=v"(pa0u[mi][0]) : "v"(sf[mi][0][0]), "v"(sf[mi][0][1]));
            asm("v_cvt_pk_bf16_f32 %0, %1, %2" : "=v"(pa0u[mi][1]) : "v"(sf[mi][0][2]), "v"(sf[mi][0][3]));
            asm("v_cvt_pk_bf16_f32 %0, %1, %2" : "=v"(pa0u[mi][2]) : "v"(sf[mi][2][0]), "v"(sf[mi][2][1]));
            asm("v_cvt_pk_bf16_f32 %0, %1, %2" : "=v"(pa0u[mi][3]) : "v"(sf[mi][2][2]), "v"(sf[mi][2][3]));
            asm("v_cvt_pk_bf16_f32 %0, %1, %2" : "=v"(pa1u[mi][0]) : "v"(sf[mi][1][0]), "v"(sf[mi][1][1]));
            asm("v_cvt_pk_bf16_f32 %0, %1, %2" : "=v"(pa1u[mi][1]) : "v"(sf[mi][1][2]), "v"(sf[mi][1][3]));
            asm("v_cvt_pk_bf16_f32 %0, %1, %2" : "=v"(pa1u[mi][2]) : "v"(sf[mi][3][0]), "v"(sf[mi][3][1]));
            asm("v_cvt_pk_bf16_f32 %0, %1, %2" : "=v"(pa1u[mi][3]) : "v"(sf[mi][3][2]), "v"(sf[mi][3][3]));

            lacc[mi] = __builtin_amdgcn_mfma_f32_16x16x32_bf16(
                __builtin_bit_cast(bf16x8, pa0u[mi]), ones, lacc[mi], 0, 0, 0);
            lacc[mi] = __builtin_amdgcn_mfma_f32_16x16x32_bf16(
                __builtin_bit_cast(bf16x8, pa1u[mi]), ones, lacc[mi], 0, 0, 0);
        }

        asm volatile("s_waitcnt vmcnt(2)" ::: "memory");
        __builtin_amdgcn_s_barrier();

        __builtin_amdgcn_s_setprio(1);
        #pragma unroll
        for (int ks = 0; ks < 2; ++ks) {
            bf16x8 vb[4];
            #pragma unroll
            for (int ni = 0; ni < 4; ++ni) {
                int rv = ni * 16 + lr;
                vb[ni] = *(const bf16x8*)&Vs[cur][rv * 64 + (((ks << 2) | lg) ^ (rv & 7)) * 8];
            }
            #pragma unroll
            for (int mi = 0; mi < 2; ++mi) {
                bf16x8 pa = __builtin_bit_cast(bf16x8, ks ? pa1u[mi] : pa0u[mi]);
                #pragma unroll
                for (int ni = 0; ni < 4; ++ni)
                    oacc[mi][ni] = __builtin_amdgcn_mfma_f32_16x16x32_bf16(pa, vb[ni], oacc[mi][ni], 0, 0, 0);
            }
        }
        __builtin_amdgcn_s_setprio(0);
    }

    if (ty == 0) {
        #pragma unroll
        for (int mi = 0; mi < 2; ++mi)
            #pragma unroll
            for (int r = 0; r < 4; ++r) {
                float inv = 1.0f / lacc[mi][r];
                int q = qw + mi * 16 + lg * 4 + r;
                size_t base = (size_t)(b * 2048 + q) * 1024 + h * 64 + lr;
                #pragma unroll
                for (int ni = 0; ni < 4; ++ni)
                    ctx[base + ni * 16] = f2bf(oacc[mi][ni][r] * inv);
            }
    } else {
        const int pidx = ((qs - 8) * 32 + bh) * 2 + (ty - 1);
        unsigned short* po = P_O + (size_t)pidx * 8192;
        #pragma unroll
        for (int mi = 0; mi < 2; ++mi)
            #pragma unroll
            for (int r = 0; r < 4; ++r) {
                int rowl = w * 32 + mi * 16 + lg * 4 + r;
                #pragma unroll
                for (int ni = 0; ni < 4; ++ni)
                    po[rowl * 64 + ni * 16 + lr] = f2bf(oacc[mi][ni][r]);
            }
        if (lr == 0) {
            #pragma unroll
            for (int mi = 0; mi < 2; ++mi)
                #pragma unroll
                for (int r = 0; r < 4; ++r)
                    P_l[pidx * 128 + w * 32 + mi * 16 + lg * 4 + r] = lacc[mi][r];
        }
    }
}

// ---------------- combine split-KV partials (shared m=0): ctx = (O0+O1)/(l0+l1) ----------------
__global__ __launch_bounds__(256)
void combine_kernel(const unsigned short* __restrict__ P_O, const float* __restrict__ P_l,
                    unsigned short* __restrict__ ctx) {
    const int qs = 8 + (blockIdx.x >> 5);
    const int bh = blockIdx.x & 31;
    const int b = bh >> 4, h = bh & 15;
    const int p0 = ((qs - 8) * 32 + bh) * 2, p1 = p0 + 1;
    const int t = threadIdx.x;
    const int row = t >> 1, half = t & 1;
    const float inv = 1.0f / (P_l[p0 * 128 + row] + P_l[p1 * 128 + row]);
    const u16x8* o0 = (const u16x8*)&P_O[(size_t)p0 * 8192 + row * 64 + half * 32];
    const u16x8* o1 = (const u16x8*)&P_O[(size_t)p1 * 8192 + row * 64 + half * 32];
    unsigned short* dst = ctx + (size_t)(b * 2048 + qs * 128 + row) * 1024 + h * 64 + half * 32;
    #pragma unroll
    for (int v = 0; v < 4; ++v) {
        u16x8 a = o0[v], c = o1[v], o;
        #pragma unroll
        for (int j = 0; j < 8; ++j)
            o[j] = f2bf((bf2f(a[j]) + bf2f(c[j])) * inv);
        ((u16x8*)dst)[v] = o;
    }
}

// ---------------- output GEMM: ctx(4096x1024) @ Wo + bo -> f32 ----------------
__global__ __launch_bounds__(256, 4)
void gemm_out_kernel(const unsigned short* __restrict__ A, const unsigned short* __restrict__ Bt,
                     float* __restrict__ C, const float* __restrict__ bias) {
    __shared__ unsigned short As[128 * 64];
    __shared__ unsigned short Bs[64 * 64];
    const int tid = threadIdx.x;
    const int w = tid >> 6, l = tid & 63;
    const int lr = l & 15, lg = l >> 4;
    const int wr = w >> 1, wc = w & 1;
    const int id = blockIdx.y * 16 + blockIdx.x;
    const int swz = (id & 7) * 64 + (id >> 3);
    const int m0 = (swz >> 4) * 128;
    const int n0 = (swz & 15) * 64;
    const int K = 1024;

    f32x4 acc[4][2] = {};

    for (int k0 = 0; k0 < 1024; k0 += 64) {
        #pragma unroll
        for (int p = 0; p < 4; ++p) {
            int seg = p * 4 + w;
            int row = seg * 8 + (l >> 3);
            int c16 = (l & 7) ^ (row & 7);
            gload16(A + (size_t)(m0 + row) * K + k0 + c16 * 8, &As[seg * 512]);
        }
        #pragma unroll
        for (int p = 0; p < 2; ++p) {
            int seg = p * 4 + w;
            int row = seg * 8 + (l >> 3);
            int c16 = (l & 7) ^ (row & 7);
            gload16(Bt + (size_t)(n0 + row) * K + k0 + c16 * 8, &Bs[seg * 512]);
        }
        __syncthreads();
        #pragma unroll
        for (int ks = 0; ks < 2; ++ks) {
            bf16x8 af[4], bfr[2];
            #pragma unroll
            for (int i = 0; i < 4; ++i) {
                int ra = wr * 64 + i * 16 + lr;
                af[i] = *(const bf16x8*)&As[ra * 64 + (((ks << 2) | lg) ^ (ra & 7)) * 8];
            }
            #pragma unroll
            for (int j = 0; j < 2; ++j) {
                int rb = wc * 32 + j * 16 + lr;
                bfr[j] = *(const bf16x8*)&Bs[rb * 64 + (((ks << 2) | lg) ^ (rb & 7)) * 8];
            }
            #pragma unroll
            for (int i = 0; i < 4; ++i)
                #pragma unroll
                for (int j = 0; j < 2; ++j)
                    acc[i][j] = __builtin_amdgcn_mfma_f32_16x16x32_bf16(af[i], bfr[j], acc[i][j], 0, 0, 0);
        }
        __syncthreads();
    }

    #pragma unroll
    for (int i = 0; i < 4; ++i)
        #pragma unroll
        for (int j = 0; j < 2; ++j) {
            int n = n0 + wc * 32 + j * 16 + lr;
            float bv = bias[n];
            #pragma unroll
            for (int r = 0; r < 4; ++r) {
                int m = m0 + wr * 64 + i * 16 + lg * 4 + r;
                C[(size_t)m * 1024 + n] = acc[i][j][r] + bv;
            }
        }
}

extern "C" void kernel_launch(void* const* d_in, const int* in_sizes, int n_in,
                              void* d_out, int out_size, void* d_ws, size_t ws_size,
                              hipStream_t stream) {
    (void)in_sizes; (void)n_in; (void)out_size; (void)ws_size;
    const float* x  = (const float*)d_in[0];
    const float* Wq = (const float*)d_in[1];
    const float* Wk = (const float*)d_in[2];
    const float* Wv = (const float*)d_in[3];
    const float* Wo = (const float*)d_in[4];
    const float* bo = (const float*)d_in[5];
    float* out = (float*)d_out;

    char* ws = (char*)d_ws;
    const size_t MB = 1024 * 1024;
    unsigned short* xb   = (unsigned short*)(ws);            // 8 MB: x bf16 (dead after qkv -> P_O)
    unsigned short* Wcat = (unsigned short*)(ws + 8  * MB);  // 6 MB (dead after qkv -> P_l)
    unsigned short* Wot  = (unsigned short*)(ws + 14 * MB);  // 2 MB: Wo^T
    unsigned short* Qb   = (unsigned short*)(ws + 16 * MB);  // 8 MB (pre-scaled by 0.125*log2e)
    unsigned short* Kb   = (unsigned short*)(ws + 24 * MB);  // 8 MB
    unsigned short* Vtb  = (unsigned short*)(ws + 32 * MB);  // 8 MB: V^T sigma-permuted
    unsigned short* Cxb  = (unsigned short*)(ws + 40 * MB);  // 8 MB: ctx bf16

    unsigned short* P_O  = (unsigned short*)(ws);            // 8 MB: 512 x 128x64 bf16 partials
    float*          P_l  = (float*)(ws + 8 * MB);            // 256 KB: 512 x 128 l values

    prep_kernel<<<dim3(16, 16, 5), 256, 0, stream>>>(x, Wq, Wk, Wv, Wo, xb, Wcat, Wot);
    gemm_qkv_kernel<<<dim3(24, 32), 256, 0, stream>>>(xb, Wcat, Qb, Kb, Vtb);
    flash_attn_kernel<<<768, 256, 0, stream>>>(Qb, Kb, Vtb, Cxb, P_O, P_l);
    combine_kernel<<<256, 256, 0, stream>>>(P_O, P_l, Cxb);
    gemm_out_kernel<<<dim3(16, 32), 256, 0, stream>>>(Cxb, Wot, out, bo);
}